// Round 2
// baseline (188.990 us; speedup 1.0000x reference)
//
#include <hip/hip_runtime.h>

typedef __bf16 bf16x8 __attribute__((ext_vector_type(8)));
typedef float f32x4 __attribute__((ext_vector_type(4)));

#define MFMA16 __builtin_amdgcn_mfma_f32_16x16x32_bf16

// Problem constants
static constexpr int BATCH = 4;
static constexpr int SEQ   = 4096;   // VQ == VK
static constexpr int CDIM  = 128;
static constexpr int HDIM  = 64;

// Load 8 contiguous fp32 and convert to bf16x8 (two float4 loads, 32B aligned)
__device__ inline bf16x8 load8f_cvt(const float* __restrict__ p) {
    f32x4 a = *reinterpret_cast<const f32x4*>(p);
    f32x4 b = *reinterpret_cast<const f32x4*>(p + 4);
    bf16x8 r;
    r[0] = (__bf16)a[0]; r[1] = (__bf16)a[1]; r[2] = (__bf16)a[2]; r[3] = (__bf16)a[3];
    r[4] = (__bf16)b[0]; r[5] = (__bf16)b[1]; r[6] = (__bf16)b[2]; r[7] = (__bf16)b[3];
    return r;
}

// ---------------------------------------------------------------------------
// proj64: out[rows][64] = bf16( (X[rows][128] @ W[128][64]) * scale )
// X, W are fp32; out is bf16. One block = 256 threads = 4 waves, 64 rows.
// ---------------------------------------------------------------------------
__global__ __launch_bounds__(256) void proj64_kernel(
    const float* __restrict__ X, const float* __restrict__ W,
    __bf16* __restrict__ out, float scale)
{
    __shared__ __bf16 Wt[64][136];   // W transposed: Wt[h][c], padded row

    const int t    = threadIdx.x;
    const int lane = t & 63;
    const int w    = t >> 6;
    const int m    = lane & 15;
    const int quad = lane >> 4;

    // Stage transposed W: 128*64 = 8192 fp32, 4 passes of 8 floats/thread
    #pragma unroll
    for (int pass = 0; pass < 4; ++pass) {
        int flat = pass * 2048 + t * 8;
        int cin  = flat >> 6;         // 0..127
        int h0   = flat & 63;         // multiple of 8
        bf16x8 v = load8f_cvt(W + flat);
        #pragma unroll
        for (int j = 0; j < 8; ++j) Wt[h0 + j][cin] = v[j];
    }
    __syncthreads();

    const long row0 = (long)blockIdx.x * 64 + w * 16;

    // A fragments: 4 K-chunks of 32 over C=128 (fp32 -> bf16)
    bf16x8 af[4];
    #pragma unroll
    for (int kc = 0; kc < 4; ++kc)
        af[kc] = load8f_cvt(X + (row0 + m) * 128 + kc * 32 + quad * 8);

    #pragma unroll
    for (int tn = 0; tn < 4; ++tn) {
        f32x4 acc = {0.f, 0.f, 0.f, 0.f};
        #pragma unroll
        for (int kc = 0; kc < 4; ++kc) {
            bf16x8 bfrag = *reinterpret_cast<const bf16x8*>(&Wt[tn * 16 + m][kc * 32 + quad * 8]);
            acc = MFMA16(af[kc], bfrag, acc, 0, 0, 0);
        }
        #pragma unroll
        for (int r = 0; r < 4; ++r) {
            int row = quad * 4 + r;
            out[(row0 + row) * 64 + tn * 16 + m] = (__bf16)(acc[r] * scale);
        }
    }
}

// ---------------------------------------------------------------------------
// proj_vt: Vt[n][c][vk] = bf16( (Y[n][vk][128] @ Wv[128][128])^T )
// Y, Wv fp32; Vt bf16 (transposed store for contiguous PV B-fragments).
// ---------------------------------------------------------------------------
__global__ __launch_bounds__(256) void proj_vt_kernel(
    const float* __restrict__ Y, const float* __restrict__ Wv,
    __bf16* __restrict__ Vt)
{
    __shared__ __bf16 Wt[128][136];  // Wv transposed: Wt[cout][cin]

    const int t    = threadIdx.x;
    const int lane = t & 63;
    const int w    = t >> 6;
    const int m    = lane & 15;
    const int quad = lane >> 4;

    // Stage transposed Wv: 128*128 = 16384 fp32, 8 passes
    #pragma unroll
    for (int pass = 0; pass < 8; ++pass) {
        int flat = pass * 2048 + t * 8;
        int cin  = flat >> 7;         // 0..127
        int co0  = flat & 127;        // multiple of 8
        bf16x8 v = load8f_cvt(Wv + flat);
        #pragma unroll
        for (int j = 0; j < 8; ++j) Wt[co0 + j][cin] = v[j];
    }
    __syncthreads();

    const long row0 = (long)blockIdx.x * 64 + w * 16;  // global row in [0, 16384)

    bf16x8 af[4];
    #pragma unroll
    for (int kc = 0; kc < 4; ++kc)
        af[kc] = load8f_cvt(Y + (row0 + m) * 128 + kc * 32 + quad * 8);

    #pragma unroll
    for (int tn = 0; tn < 8; ++tn) {
        f32x4 acc = {0.f, 0.f, 0.f, 0.f};
        #pragma unroll
        for (int kc = 0; kc < 4; ++kc) {
            bf16x8 bfrag = *reinterpret_cast<const bf16x8*>(&Wt[tn * 16 + m][kc * 32 + quad * 8]);
            acc = MFMA16(af[kc], bfrag, acc, 0, 0, 0);
        }
        #pragma unroll
        for (int r = 0; r < 4; ++r) {
            long row = row0 + quad * 4 + r;      // n*4096 + key
            long n   = row >> 12;
            long key = row & 4095;
            Vt[(n * 128 + tn * 16 + m) * (long)SEQ + key] = (__bf16)acc[r];
        }
    }
}

// ---------------------------------------------------------------------------
// Flash attention: one block per (batch, 64-row q-tile); 4 waves, 16 rows/wave.
// Q pre-scaled by H^-0.5 * log2(e) -> exp2 softmax. Output fp32.
// ---------------------------------------------------------------------------
__global__ __launch_bounds__(256) void attn_kernel(
    const __bf16* __restrict__ Q, const __bf16* __restrict__ K,
    const __bf16* __restrict__ Vt, float* __restrict__ out)
{
    __shared__ __bf16 Ks[64][72];        // K tile  [key][h]   9216 B
    __shared__ __bf16 Vs[128][72];       // Vt tile [c][key]  18432 B
    __shared__ __bf16 Ps[4][16][72];     // per-wave P scratch 9216 B

    const int t    = threadIdx.x;
    const int lane = t & 63;
    const int w    = t >> 6;
    const int m    = lane & 15;
    const int quad = lane >> 4;

    const int bx = blockIdx.x;
    const int n  = bx >> 6;              // batch
    const int q0 = (bx & 63) * 64;       // q-tile base

    const __bf16* Qn = Q  + (long)n * SEQ * HDIM;
    const __bf16* Kn = K  + (long)n * SEQ * HDIM;
    const __bf16* Vn = Vt + (long)n * CDIM * SEQ;

    // Q A-fragments (kept in registers for all iterations)
    bf16x8 qf[2];
    #pragma unroll
    for (int kc = 0; kc < 2; ++kc)
        qf[kc] = *reinterpret_cast<const bf16x8*>(Qn + (q0 + w * 16 + m) * 64 + kc * 32 + quad * 8);

    float m_run[4], l_run[4];
    f32x4 o_acc[8];
    const f32x4 fzero = {0.f, 0.f, 0.f, 0.f};
    #pragma unroll
    for (int i = 0; i < 8; ++i) o_acc[i] = fzero;
    #pragma unroll
    for (int r = 0; r < 4; ++r) { m_run[r] = -__builtin_inff(); l_run[r] = 0.f; }

    for (int kt = 0; kt < SEQ / 64; ++kt) {
        const int k0 = kt * 64;
        // --- stage K tile: 64x64 bf16 ---
        #pragma unroll
        for (int pass = 0; pass < 2; ++pass) {
            int idx = pass * 256 + t;
            int key = idx >> 3, h0 = (idx & 7) * 8;
            bf16x8 v = *reinterpret_cast<const bf16x8*>(Kn + (long)(k0 + key) * 64 + h0);
            *reinterpret_cast<bf16x8*>(&Ks[key][h0]) = v;
        }
        // --- stage V tile (transposed layout): 128x64 ---
        #pragma unroll
        for (int pass = 0; pass < 4; ++pass) {
            int idx = pass * 256 + t;
            int c = idx >> 3, ks = (idx & 7) * 8;
            bf16x8 v = *reinterpret_cast<const bf16x8*>(Vn + (long)c * SEQ + k0 + ks);
            *reinterpret_cast<bf16x8*>(&Vs[c][ks]) = v;
        }
        __syncthreads();

        // --- S = Q K^T : [16 x 64], 4 col-tiles x 2 k-chunks ---
        f32x4 s[4];
        #pragma unroll
        for (int tn = 0; tn < 4; ++tn) {
            f32x4 a = fzero;
            #pragma unroll
            for (int kc = 0; kc < 2; ++kc) {
                bf16x8 kb = *reinterpret_cast<const bf16x8*>(&Ks[tn * 16 + m][kc * 32 + quad * 8]);
                a = MFMA16(qf[kc], kb, a, 0, 0, 0);
            }
            s[tn] = a;
        }

        // --- online softmax (row = quad*4 + r; 16 lanes of a quad share rows) ---
        float p[4][4];
        #pragma unroll
        for (int r = 0; r < 4; ++r) {
            float cm = fmaxf(fmaxf(s[0][r], s[1][r]), fmaxf(s[2][r], s[3][r]));
            #pragma unroll
            for (int off = 1; off < 16; off <<= 1)
                cm = fmaxf(cm, __shfl_xor(cm, off, 64));
            float mn = fmaxf(m_run[r], cm);
            float alpha = __builtin_amdgcn_exp2f(m_run[r] - mn);
            m_run[r] = mn;
            float psum = 0.f;
            #pragma unroll
            for (int tn = 0; tn < 4; ++tn) {
                float pv = __builtin_amdgcn_exp2f(s[tn][r] - mn);
                p[tn][r] = pv;
                psum += pv;
            }
            l_run[r] = l_run[r] * alpha + psum;
            #pragma unroll
            for (int nt = 0; nt < 8; ++nt) o_acc[nt][r] *= alpha;
        }

        // --- P: C/D layout -> LDS -> A layout ---
        #pragma unroll
        for (int tn = 0; tn < 4; ++tn)
            #pragma unroll
            for (int r = 0; r < 4; ++r)
                Ps[w][quad * 4 + r][tn * 16 + m] = (__bf16)p[tn][r];
        __syncthreads();

        // --- O += P V : 8 col-tiles x 2 k-chunks ---
        #pragma unroll
        for (int kc = 0; kc < 2; ++kc) {
            bf16x8 pf = *reinterpret_cast<const bf16x8*>(&Ps[w][m][kc * 32 + quad * 8]);
            #pragma unroll
            for (int nt = 0; nt < 8; ++nt) {
                bf16x8 vf = *reinterpret_cast<const bf16x8*>(&Vs[nt * 16 + m][kc * 32 + quad * 8]);
                o_acc[nt] = MFMA16(pf, vf, o_acc[nt], 0, 0, 0);
            }
        }
        __syncthreads();
    }

    // --- finalize: l = cross-lane row sum, divide, store fp32 ---
    #pragma unroll
    for (int r = 0; r < 4; ++r) {
        float l = l_run[r];
        #pragma unroll
        for (int off = 1; off < 16; off <<= 1) l += __shfl_xor(l, off, 64);
        l_run[r] = 1.0f / l;
    }
    #pragma unroll
    for (int nt = 0; nt < 8; ++nt)
        #pragma unroll
        for (int r = 0; r < 4; ++r) {
            long row = (long)n * SEQ + q0 + w * 16 + quad * 4 + r;
            out[row * CDIM + nt * 16 + m] = o_acc[nt][r] * l_run[r];
        }
}

// ---------------------------------------------------------------------------
extern "C" void kernel_launch(void* const* d_in, const int* in_sizes, int n_in,
                              void* d_out, int out_size, void* d_ws, size_t ws_size,
                              hipStream_t stream)
{
    const float* x  = (const float*)d_in[0];  // [4,4096,128] fp32
    const float* y  = (const float*)d_in[1];  // [4,4096,128] fp32
    const float* Wq = (const float*)d_in[2];  // [128,64]     fp32
    const float* Wk = (const float*)d_in[3];  // [128,64]     fp32
    const float* Wv = (const float*)d_in[4];  // [128,128]    fp32
    float* out = (float*)d_out;               // [4,4096,128] fp32

    __bf16* Qw  = (__bf16*)d_ws;                         // [4,4096,64]  2 MB
    __bf16* Kw  = Qw + (long)BATCH * SEQ * HDIM;         // [4,4096,64]  2 MB
    __bf16* Vtw = Kw + (long)BATCH * SEQ * HDIM;         // [4,128,4096] 4 MB

    // scale = H^-0.5 * log2(e), folded into Q before bf16 rounding
    const float qscale = 0.125f * 1.4426950408889634f;

    const int rows = BATCH * SEQ;                // 16384
    proj64_kernel<<<dim3(rows / 64), dim3(256), 0, stream>>>(x, Wq, Qw, qscale);
    proj64_kernel<<<dim3(rows / 64), dim3(256), 0, stream>>>(y, Wk, Kw, 1.0f);
    proj_vt_kernel<<<dim3(rows / 64), dim3(256), 0, stream>>>(y, Wv, Vtw);

    attn_kernel<<<dim3(BATCH * (SEQ / 64)), dim3(256), 0, stream>>>(Qw, Kw, Vtw, out);
}

// Round 3
// 137.612 us; speedup vs baseline: 1.3734x; 1.3734x over previous
//
#include <hip/hip_runtime.h>

typedef __bf16 bf16x8 __attribute__((ext_vector_type(8)));
typedef __bf16 bf16x4 __attribute__((ext_vector_type(4)));
typedef float  f32x4  __attribute__((ext_vector_type(4)));

#define MFMA16 __builtin_amdgcn_mfma_f32_16x16x32_bf16

static constexpr int BATCH = 4;
static constexpr int SEQ   = 4096;
static constexpr int CDIM  = 128;
static constexpr int HDIM  = 64;

// Load 8 contiguous fp32 and convert to bf16x8
__device__ inline bf16x8 load8f_cvt(const float* __restrict__ p) {
    f32x4 a = *reinterpret_cast<const f32x4*>(p);
    f32x4 b = *reinterpret_cast<const f32x4*>(p + 4);
    bf16x8 r;
    r[0] = (__bf16)a[0]; r[1] = (__bf16)a[1]; r[2] = (__bf16)a[2]; r[3] = (__bf16)a[3];
    r[4] = (__bf16)b[0]; r[5] = (__bf16)b[1]; r[6] = (__bf16)b[2]; r[7] = (__bf16)b[3];
    return r;
}

// ---------------------------------------------------------------------------
// Fused projections: one launch, 768 blocks.
//   job 0 (blocks   0-255): Q  = x @ Wq * qscale      -> Qw  [16384][64] bf16
//   job 1 (blocks 256-511): K  = y @ Wk               -> Kw  [16384][64] bf16
//   job 2 (blocks 512-767): Vt = (y @ Wv)^T per batch -> Vtw [4][128][4096] bf16
// ---------------------------------------------------------------------------
__global__ __launch_bounds__(256) void proj_all_kernel(
    const float* __restrict__ x, const float* __restrict__ y,
    const float* __restrict__ Wq, const float* __restrict__ Wk,
    const float* __restrict__ Wv,
    __bf16* __restrict__ Qw, __bf16* __restrict__ Kw, __bf16* __restrict__ Vtw,
    float qscale)
{
    __shared__ __bf16 Wt[128][136];   // transposed weight: Wt[cout][cin]

    const int job = blockIdx.x >> 8;
    const int bx  = blockIdx.x & 255;
    const int t    = threadIdx.x;
    const int lane = t & 63;
    const int w    = t >> 6;
    const int m    = lane & 15;
    const int quad = lane >> 4;

    if (job <= 1) {
        const float* X   = job ? y  : x;
        const float* W   = job ? Wk : Wq;
        __bf16*      out = job ? Kw : Qw;
        const float scale = job ? 1.0f : qscale;

        // Stage W^T: 128x64 fp32 -> bf16
        #pragma unroll
        for (int pass = 0; pass < 4; ++pass) {
            int flat = pass * 2048 + t * 8;
            int cin  = flat >> 6;
            int h0   = flat & 63;
            bf16x8 v = load8f_cvt(W + flat);
            #pragma unroll
            for (int j = 0; j < 8; ++j) Wt[h0 + j][cin] = v[j];
        }
        __syncthreads();

        const long row0 = (long)bx * 64 + w * 16;
        bf16x8 af[4];
        #pragma unroll
        for (int kc = 0; kc < 4; ++kc)
            af[kc] = load8f_cvt(X + (row0 + m) * 128 + kc * 32 + quad * 8);

        #pragma unroll
        for (int tn = 0; tn < 4; ++tn) {
            f32x4 acc = {0.f, 0.f, 0.f, 0.f};
            #pragma unroll
            for (int kc = 0; kc < 4; ++kc) {
                bf16x8 bfrag = *reinterpret_cast<const bf16x8*>(&Wt[tn * 16 + m][kc * 32 + quad * 8]);
                acc = MFMA16(af[kc], bfrag, acc, 0, 0, 0);
            }
            #pragma unroll
            for (int r = 0; r < 4; ++r)
                out[(row0 + quad * 4 + r) * 64 + tn * 16 + m] = (__bf16)(acc[r] * scale);
        }
    } else {
        // V projection with transposed store
        #pragma unroll
        for (int pass = 0; pass < 8; ++pass) {
            int flat = pass * 2048 + t * 8;
            int cin  = flat >> 7;
            int co0  = flat & 127;
            bf16x8 v = load8f_cvt(Wv + flat);
            #pragma unroll
            for (int j = 0; j < 8; ++j) Wt[co0 + j][cin] = v[j];
        }
        __syncthreads();

        const long row0 = (long)bx * 64 + w * 16;
        bf16x8 af[4];
        #pragma unroll
        for (int kc = 0; kc < 4; ++kc)
            af[kc] = load8f_cvt(y + (row0 + m) * 128 + kc * 32 + quad * 8);

        #pragma unroll
        for (int tn = 0; tn < 8; ++tn) {
            f32x4 acc = {0.f, 0.f, 0.f, 0.f};
            #pragma unroll
            for (int kc = 0; kc < 4; ++kc) {
                bf16x8 bfrag = *reinterpret_cast<const bf16x8*>(&Wt[tn * 16 + m][kc * 32 + quad * 8]);
                acc = MFMA16(af[kc], bfrag, acc, 0, 0, 0);
            }
            #pragma unroll
            for (int r = 0; r < 4; ++r) {
                long row = row0 + quad * 4 + r;      // n*4096 + key
                long n   = row >> 12;
                long key = row & 4095;
                Vtw[(n * 128 + tn * 16 + m) * (long)SEQ + key] = (__bf16)acc[r];
            }
        }
    }
}

// ---------------------------------------------------------------------------
// Flash attention, transposed-S orientation, in-block K-split x2.
// Block = 512 threads = 8 waves. Waves 0-3: keys [0,2048); waves 4-7: [2048,4096).
// Each wave owns 16 q-rows (q = q0 + (w&3)*16 + lane&15, per-lane softmax state).
// S^T = MFMA(K-frag, Q-frag); O^T = MFMA(Vt-frag, P^T-frag). Output store f32x4.
// ---------------------------------------------------------------------------
__global__ __launch_bounds__(512, 2) void attn_kernel(
    const __bf16* __restrict__ Q, const __bf16* __restrict__ K,
    const __bf16* __restrict__ Vt, float* __restrict__ out)
{
    // LDS layout (bytes):
    //   [0,      18432): Ks[2][64][72]   K staging, per key-group
    //   [18432,  55296): Vs[2][128][72]  V staging, per key-group
    //   [55296,  73728): Ps[8][16][72]   per-wave P scratch (C->A layout)
    //   epilogue overlay at [0, 36864): merge buffer (4 waves x 64 lanes x 36 f32)
    __shared__ __align__(16) char smem[73728];
    __bf16* const KsBase = (__bf16*)smem;
    __bf16* const VsBase = (__bf16*)(smem + 18432);
    __bf16* const PsBase = (__bf16*)(smem + 55296);
    float*  const mg     = (float*)smem;

    const int t    = threadIdx.x;
    const int lane = t & 63;
    const int w    = t >> 6;
    const int m    = lane & 15;
    const int quad = lane >> 4;
    const int g    = w >> 2;     // key-group 0/1
    const int wg   = w & 3;      // wave-in-group = q row tile
    const int tg   = t & 255;    // thread-in-group

    const int bx = blockIdx.x;
    const int n  = bx >> 6;
    const int q0 = (bx & 63) * 64;

    const __bf16* Qn = Q  + (long)n * SEQ * HDIM;
    const __bf16* Kn = K  + (long)n * SEQ * HDIM;
    const __bf16* Vn = Vt + (long)n * CDIM * SEQ;

    __bf16* const Ksg = KsBase + g * 4608;    // 64*72 elems
    __bf16* const Vsg = VsBase + g * 9216;    // 128*72 elems
    __bf16* const Psw = PsBase + w * 1152;    // 16*72 elems

    // Q fragments (B-operand data): Q[q0+wg*16+m][kc*32+quad*8 ..]
    bf16x8 qf[2];
    #pragma unroll
    for (int kc = 0; kc < 2; ++kc)
        qf[kc] = *reinterpret_cast<const bf16x8*>(Qn + (q0 + wg * 16 + m) * 64 + kc * 32 + quad * 8);

    float m_run = -__builtin_inff();
    float l_run = 0.f;
    f32x4 o_acc[8];
    const f32x4 fzero = {0.f, 0.f, 0.f, 0.f};
    #pragma unroll
    for (int i = 0; i < 8; ++i) o_acc[i] = fzero;

    const long gk = (long)g * 2048;
    bf16x8 kr[2], vr[4];

    // prefetch tile 0
    {
        const long k0 = gk;
        #pragma unroll
        for (int p = 0; p < 2; ++p) {
            int idx = p * 256 + tg;
            kr[p] = *reinterpret_cast<const bf16x8*>(Kn + (k0 + (idx >> 3)) * 64 + (idx & 7) * 8);
        }
        #pragma unroll
        for (int p = 0; p < 4; ++p) {
            int idx = p * 256 + tg;
            vr[p] = *reinterpret_cast<const bf16x8*>(Vn + (long)(idx >> 3) * SEQ + k0 + (idx & 7) * 8);
        }
    }

    for (int kt = 0; kt < 32; ++kt) {
        __syncthreads();   // previous compute done; staging LDS writable
        #pragma unroll
        for (int p = 0; p < 2; ++p) {
            int idx = p * 256 + tg;
            *reinterpret_cast<bf16x8*>(Ksg + (idx >> 3) * 72 + (idx & 7) * 8) = kr[p];
        }
        #pragma unroll
        for (int p = 0; p < 4; ++p) {
            int idx = p * 256 + tg;
            *reinterpret_cast<bf16x8*>(Vsg + (idx >> 3) * 72 + (idx & 7) * 8) = vr[p];
        }
        if (kt < 31) {     // prefetch next tile; latency overlaps compute below
            const long k0 = gk + (kt + 1) * 64;
            #pragma unroll
            for (int p = 0; p < 2; ++p) {
                int idx = p * 256 + tg;
                kr[p] = *reinterpret_cast<const bf16x8*>(Kn + (k0 + (idx >> 3)) * 64 + (idx & 7) * 8);
            }
            #pragma unroll
            for (int p = 0; p < 4; ++p) {
                int idx = p * 256 + tg;
                vr[p] = *reinterpret_cast<const bf16x8*>(Vn + (long)(idx >> 3) * SEQ + k0 + (idx & 7) * 8);
            }
        }
        __syncthreads();   // tiles ready

        // --- S^T = K·Q^T : lane holds S[q=m][key=tn*16+quad*4+r] ---
        f32x4 s[4];
        #pragma unroll
        for (int tn = 0; tn < 4; ++tn) {
            f32x4 a = fzero;
            #pragma unroll
            for (int kc = 0; kc < 2; ++kc) {
                bf16x8 kb = *reinterpret_cast<const bf16x8*>(Ksg + (tn * 16 + m) * 72 + kc * 32 + quad * 8);
                a = MFMA16(kb, qf[kc], a, 0, 0, 0);
            }
            s[tn] = a;
        }

        // --- per-lane online softmax (row q=m spans the 4 quads) ---
        float cm = -__builtin_inff();
        #pragma unroll
        for (int tn = 0; tn < 4; ++tn)
            #pragma unroll
            for (int r = 0; r < 4; ++r) cm = fmaxf(cm, s[tn][r]);
        cm = fmaxf(cm, __shfl_xor(cm, 16, 64));
        cm = fmaxf(cm, __shfl_xor(cm, 32, 64));
        float mn    = fmaxf(m_run, cm);
        float alpha = __builtin_amdgcn_exp2f(m_run - mn);
        m_run = mn;

        float psum = 0.f;
        #pragma unroll
        for (int tn = 0; tn < 4; ++tn) {
            bf16x4 pk;
            #pragma unroll
            for (int r = 0; r < 4; ++r) {
                float pv = __builtin_amdgcn_exp2f(s[tn][r] - mn);
                psum += pv;
                pk[r] = (__bf16)pv;
            }
            // P[q=m][keys tn*16+quad*4 .. +3] packed as one b64 write
            *reinterpret_cast<bf16x4*>(Psw + m * 72 + tn * 16 + quad * 4) = pk;
        }
        psum += __shfl_xor(psum, 16, 64);
        psum += __shfl_xor(psum, 32, 64);
        l_run = l_run * alpha + psum;
        #pragma unroll
        for (int nt = 0; nt < 8; ++nt) o_acc[nt] *= alpha;

        // Ps is wave-private: wave-local LDS drain suffices (no block barrier)
        __asm__ volatile("s_waitcnt lgkmcnt(0)" ::: "memory");

        // --- O^T += Vt·P^T : lane accumulates O[q=m][c=nt*16+quad*4+r] ---
        #pragma unroll
        for (int kc = 0; kc < 2; ++kc) {
            bf16x8 pf = *reinterpret_cast<const bf16x8*>(Psw + m * 72 + kc * 32 + quad * 8);
            #pragma unroll
            for (int nt = 0; nt < 8; ++nt) {
                bf16x8 vf = *reinterpret_cast<const bf16x8*>(Vsg + (nt * 16 + m) * 72 + kc * 32 + quad * 8);
                o_acc[nt] = MFMA16(vf, pf, o_acc[nt], 0, 0, 0);
            }
        }
    }

    // --- merge the two key-groups (overlay staging LDS) ---
    __syncthreads();
    if (g == 1) {
        float* dst = mg + (wg * 64 + lane) * 36;
        #pragma unroll
        for (int nt = 0; nt < 8; ++nt)
            #pragma unroll
            for (int r = 0; r < 4; ++r) dst[nt * 4 + r] = o_acc[nt][r];
        dst[32] = m_run;
        dst[33] = l_run;
    }
    __syncthreads();
    if (g == 0) {
        const float* src = mg + (wg * 64 + lane) * 36;
        float m2 = src[32], l2 = src[33];
        float M  = fmaxf(m_run, m2);
        float a1 = __builtin_amdgcn_exp2f(m_run - M);
        float a2 = __builtin_amdgcn_exp2f(m2 - M);
        float inv = 1.0f / (l_run * a1 + l2 * a2);
        const long row = (long)n * SEQ + q0 + wg * 16 + m;
        #pragma unroll
        for (int nt = 0; nt < 8; ++nt) {
            f32x4 o;
            #pragma unroll
            for (int r = 0; r < 4; ++r)
                o[r] = (o_acc[nt][r] * a1 + src[nt * 4 + r] * a2) * inv;
            *reinterpret_cast<f32x4*>(out + row * CDIM + nt * 16 + quad * 4) = o;
        }
    }
}

// ---------------------------------------------------------------------------
extern "C" void kernel_launch(void* const* d_in, const int* in_sizes, int n_in,
                              void* d_out, int out_size, void* d_ws, size_t ws_size,
                              hipStream_t stream)
{
    const float* x  = (const float*)d_in[0];  // [4,4096,128] fp32
    const float* y  = (const float*)d_in[1];  // [4,4096,128] fp32
    const float* Wq = (const float*)d_in[2];  // [128,64]     fp32
    const float* Wk = (const float*)d_in[3];  // [128,64]     fp32
    const float* Wv = (const float*)d_in[4];  // [128,128]    fp32
    float* out = (float*)d_out;               // [4,4096,128] fp32

    __bf16* Qw  = (__bf16*)d_ws;                         // [4,4096,64]  2 MB
    __bf16* Kw  = Qw + (long)BATCH * SEQ * HDIM;         // [4,4096,64]  2 MB
    __bf16* Vtw = Kw + (long)BATCH * SEQ * HDIM;         // [4,128,4096] 4 MB

    // scale = H^-0.5 * log2(e), folded into Q before bf16 rounding
    const float qscale = 0.125f * 1.4426950408889634f;

    proj_all_kernel<<<dim3(768), dim3(256), 0, stream>>>(
        x, y, Wq, Wk, Wv, Qw, Kw, Vtw, qscale);

    attn_kernel<<<dim3(BATCH * (SEQ / 64)), dim3(512), 0, stream>>>(Qw, Kw, Vtw, out);
}